// Round 17
// baseline (205.871 us; speedup 1.0000x reference)
//
#include <hip/hip_runtime.h>
#include <hip/hip_fp16.h>

#define NNODES 100000
#define NEDGES 800000
#define NGRAPHS 5000
#define FN 11
#define FE 4
#define H1C 32
#define H2C 16

typedef _Float16 half8 __attribute__((ext_vector_type(8)));
typedef float f32x4 __attribute__((ext_vector_type(4)));

__device__ __forceinline__ void pk_atomic_add(_Float16* p, float a, float b) {
  __half2 v = __floats2half2_rn(a, b);
  unsafeAtomicAdd(reinterpret_cast<__half2*>(p), v);
}

// Fused: zero agg1 (400k int4) + pre-swizzle B1 (12288 f16) and B2 (16384 f16).
__global__ __launch_bounds__(256) void k_prep(const float* __restrict__ c1w2,
    const float* __restrict__ c1b2, _Float16* __restrict__ B1h,
    const float* __restrict__ c2w2, _Float16* __restrict__ B2h,
    _Float16* __restrict__ agg1) {
  int t = blockIdx.x * 256 + threadIdx.x;
  if (t < NNODES * H1C / 8) {
    int4 z = {0, 0, 0, 0};
    reinterpret_cast<int4*>(agg1)[t] = z;
  }
  if (t < 2 * 12 * 64 * 8) {
    int j = t & 7;
    int lane = (t >> 3) & 63;
    int rest = t >> 9;
    int step = rest % 12;
    int ot = rest / 12;
    int q = (lane >> 4) * 8 + j;
    int o = (lane & 15) + ot * 16;
    float v;
    if (step < 11) v = c1w2[q * (FN * H1C) + step * H1C + o];
    else v = (q < FN) ? c1b2[q * H1C + o] : 0.f;
    B1h[t] = (_Float16)v;
  } else if (t < 2 * 12 * 64 * 8 + 32 * 64 * 8) {
    int t2 = t - 2 * 12 * 64 * 8;
    int kk = t2 >> 9;
    int l = (t2 >> 3) & 63;
    int j = t2 & 7;
    int i = (l >> 4) * 8 + j;
    int o = l & 15;
    B2h[t2] = (_Float16)c2w2[(kk * 32 + i) * H2C + o];
  }
}

// conv1 edge pass via MFMA — EXACT r13/r15 structure (50.5 µs verified;
// at the coalesced-atomic channel ceiling, do not touch).
__global__ __launch_bounds__(256, 3) void k_edge1_mfma(
    const float* __restrict__ x, const int* __restrict__ ei,
    const float* __restrict__ ea, const float* __restrict__ w1,
    const float* __restrict__ b1, const _Float16* __restrict__ B1h,
    _Float16* __restrict__ agg1) {
  __shared__ _Float16 Bl[12288];        // 24 KB B-frags
  __shared__ _Float16 h_sl[4][256][8];  // 16 KB h slices
  __shared__ _Float16 xs_sl[2][256][8]; // 8 KB xs slices (slices 2,3 all-zero)
  __shared__ int s_dst[256];
  int tid = threadIdx.x;
  {
    const int4* s = (const int4*)B1h;   // 1536 int4
    int4* d = (int4*)Bl;
    #pragma unroll
    for (int q = 0; q < 6; q++) d[q * 256 + tid] = s[q * 256 + tid];
  }
  int e = blockIdx.x * 256 + tid;   // NEDGES % 256 == 0
  int src = ei[e];
  s_dst[tid] = ei[NEDGES + e];
  float4 a4 = *reinterpret_cast<const float4*>(ea + e * 4);
  float h[32];
  #pragma unroll
  for (int k = 0; k < 32; k++) {
    float v = b1[k] + a4.x * w1[k] + a4.y * w1[32 + k] + a4.z * w1[64 + k] + a4.w * w1[96 + k];
    h[k] = v > 0.f ? v : 0.f;
  }
  #pragma unroll
  for (int s = 0; s < 4; s++) {
    half8 t8;
    #pragma unroll
    for (int j = 0; j < 8; j++) t8[j] = (_Float16)h[s * 8 + j];
    *reinterpret_cast<half8*>(&h_sl[s][tid][0]) = t8;
  }
  float xsv[FN];
  #pragma unroll
  for (int i = 0; i < FN; i++) xsv[i] = x[src * FN + i];
  #pragma unroll
  for (int s = 0; s < 2; s++) {
    half8 t8;
    #pragma unroll
    for (int j = 0; j < 8; j++) {
      int k = s * 8 + j;
      t8[j] = (k < FN) ? (_Float16)xsv[k] : (_Float16)0.f;
    }
    *reinterpret_cast<half8*>(&xs_sl[s][tid][0]) = t8;
  }
  __syncthreads();
  int lane = tid & 63;
  int w = tid >> 6;
  int halfk = lane >> 4;
  int er = lane & 15;
  #pragma unroll 1
  for (int g = 0; g < 4; g++) {
    int eb = w * 64 + g * 16;
    int el = eb + er;
    half8 hs8 = *reinterpret_cast<const half8*>(&h_sl[halfk][el][0]);
    half8 xs8;
    if (halfk < 2) xs8 = *reinterpret_cast<const half8*>(&xs_sl[halfk][el][0]);
    else xs8 = half8{};   // K rows 16..31 of the bias step are zero
    f32x4 acc0 = {0.f, 0.f, 0.f, 0.f};
    f32x4 acc1 = {0.f, 0.f, 0.f, 0.f};
    {
      half8 b0 = *reinterpret_cast<const half8*>(&Bl[11 * 512 + lane * 8]);
      half8 b1f = *reinterpret_cast<const half8*>(&Bl[6144 + 11 * 512 + lane * 8]);
      acc0 = __builtin_amdgcn_mfma_f32_16x16x32_f16(xs8, b0, acc0, 0, 0, 0);
      acc1 = __builtin_amdgcn_mfma_f32_16x16x32_f16(xs8, b1f, acc1, 0, 0, 0);
    }
    #pragma unroll
    for (int i = 0; i < FN; i++) {
      _Float16 xh = xs_sl[i >> 3][el][i & 7];
      half8 xsp;
      #pragma unroll
      for (int j = 0; j < 8; j++) xsp[j] = xh;
      half8 af = xsp * hs8;            // v_pk_mul_f16 x4
      half8 b0 = *reinterpret_cast<const half8*>(&Bl[i * 512 + lane * 8]);
      half8 b1f = *reinterpret_cast<const half8*>(&Bl[6144 + i * 512 + lane * 8]);
      acc0 = __builtin_amdgcn_mfma_f32_16x16x32_f16(af, b0, acc0, 0, 0, 0);
      acc1 = __builtin_amdgcn_mfma_f32_16x16x32_f16(af, b1f, acc1, 0, 0, 0);
    }
    #pragma unroll
    for (int r = 0; r < 4; r++) {
      int d = s_dst[eb + halfk * 4 + r];
      float p0 = __shfl_xor(acc0[r], 1, 64);
      float p1 = __shfl_xor(acc1[r], 1, 64);
      int odd = er & 1;
      int ch = odd ? (16 + er - 1) : er;
      float lo = odd ? p1 : acc0[r];
      float hi = odd ? acc1[r] : p0;
      pk_atomic_add(&agg1[d * H1C + ch], lo, hi);
    }
  }
}

// Fused: base = c1_bias + x@c1_root (block-staged);
// h1h = f16(relu(agg1 + base)); agg2 base = f16(c2_bias + relu@c2_root).
__global__ __launch_bounds__(256) void k_mid(const float* __restrict__ x,
    const _Float16* __restrict__ agg1, const float* __restrict__ root1,
    const float* __restrict__ bias1, const float* __restrict__ root2,
    const float* __restrict__ bias2, _Float16* __restrict__ h1h,
    _Float16* __restrict__ agg2) {
  __shared__ float sbase[16][33];
  int tid = threadIdx.x;
  int t = blockIdx.x * 256 + tid;   // NNODES*16 % 256 == 0
  int n = t >> 4, o = t & 15;
  int nl = tid >> 4;
  {
    float b0 = bias1[o], b16 = bias1[o + 16];
    #pragma unroll
    for (int i = 0; i < FN; i++) {
      float xv = x[n * FN + i];
      b0 += xv * root1[i * H1C + o];
      b16 += xv * root1[i * H1C + o + 16];
    }
    sbase[nl][o] = b0;
    sbase[nl][o + 16] = b16;
  }
  __syncthreads();
  float hv[32];
  #pragma unroll
  for (int i = 0; i < 32; i++) {
    float v = (float)agg1[n * H1C + i] + sbase[nl][i];
    hv[i] = v > 0.f ? v : 0.f;
  }
  h1h[n * H1C + o] = (_Float16)hv[o];
  h1h[n * H1C + o + 16] = (_Float16)hv[o + 16];
  float acc = bias2[o];
  #pragma unroll
  for (int i = 0; i < 32; i++) acc += hv[i] * root2[i * H2C + o];
  agg2[n * H2C + o] = (_Float16)acc;
}

// conv2 edge pass — r16 structure at 512 threads/block: Bl shared by 8 waves,
// LDS/CU 153 -> 136 KB, waves/CU 12 -> 16. Tail guarded with zeroed h rows
// (contribution exactly 0.0 -> harmless atomic).
__global__ __launch_bounds__(512, 4) void k_edge2_mfma(
    const _Float16* __restrict__ h1h, const int* __restrict__ ei,
    const float* __restrict__ ea, const float* __restrict__ w1,
    const float* __restrict__ b1, const _Float16* __restrict__ B2h,
    _Float16* __restrict__ agg2) {
  __shared__ _Float16 Bl[16384];         // 32 KB
  __shared__ _Float16 h_sl2[4][512][8];  // 32 KB, slice-major (16B rows)
  __shared__ int s_src[512];
  __shared__ int s_dst[512];
  int tid = threadIdx.x;
  {
    const int4* s = (const int4*)B2h;    // 2048 int4
    int4* d = (int4*)Bl;
    #pragma unroll
    for (int q = 0; q < 4; q++) d[q * 512 + tid] = s[q * 512 + tid];
  }
  int e = blockIdx.x * 512 + tid;
  bool valid = e < NEDGES;
  int e_c = valid ? e : 0;
  s_src[tid] = ei[e_c];
  s_dst[tid] = valid ? ei[NEDGES + e_c] : 0;
  float4 a4 = *reinterpret_cast<const float4*>(ea + (size_t)e_c * 4);
  #pragma unroll
  for (int s = 0; s < 4; s++) {
    half8 t8;
    #pragma unroll
    for (int j = 0; j < 8; j++) {
      int k = s * 8 + j;
      float v = b1[k] + a4.x * w1[k] + a4.y * w1[32 + k] + a4.z * w1[64 + k] + a4.w * w1[96 + k];
      v = v > 0.f ? v : 0.f;
      t8[j] = valid ? (_Float16)v : (_Float16)0.f;
    }
    *reinterpret_cast<half8*>(&h_sl2[s][tid][0]) = t8;
  }
  __syncthreads();
  int lane = tid & 63;
  int w = tid >> 6;        // 0..7
  int halfk = lane >> 4;
  int er = lane & 15;
  int sn0 = s_src[w * 64 + er];
  half8 hsb_cur = *reinterpret_cast<const half8*>(h1h + sn0 * H1C + halfk * 8);
  #pragma unroll 1
  for (int g = 0; g < 4; g++) {
    int eb = w * 64 + g * 16;
    int el = eb + er;
    half8 hsb_next = half8{};
    if (g < 3) {
      int sn2 = s_src[eb + 16 + er];
      hsb_next = *reinterpret_cast<const half8*>(h1h + sn2 * H1C + halfk * 8);
    }
    half8 hr0 = *reinterpret_cast<const half8*>(&h_sl2[0][el][0]);
    half8 hr1 = *reinterpret_cast<const half8*>(&h_sl2[1][el][0]);
    half8 hr2 = *reinterpret_cast<const half8*>(&h_sl2[2][el][0]);
    half8 hr3 = *reinterpret_cast<const half8*>(&h_sl2[3][el][0]);
    f32x4 acc = {0.f, 0.f, 0.f, 0.f};
    #pragma unroll
    for (int kk = 0; kk < 32; kk++) {
      _Float16 hv = (kk < 8) ? hr0[kk & 7]
                  : (kk < 16) ? hr1[kk & 7]
                  : (kk < 24) ? hr2[kk & 7]
                  : hr3[kk & 7];
      half8 hsp;
      #pragma unroll
      for (int j = 0; j < 8; j++) hsp[j] = hv;
      half8 af = hsp * hsb_cur;        // v_pk_mul_f16 x4
      half8 bfrag = *reinterpret_cast<const half8*>(&Bl[(kk * 64 + lane) * 8]);
      acc = __builtin_amdgcn_mfma_f32_16x16x32_f16(af, bfrag, acc, 0, 0, 0);
    }
    #pragma unroll
    for (int r2 = 0; r2 < 4; r2 += 2) {
      int d_e = s_dst[eb + halfk * 4 + r2];
      int d_o = s_dst[eb + halfk * 4 + r2 + 1];
      float pe = __shfl_xor(acc[r2], 1, 64);
      float po = __shfl_xor(acc[r2 + 1], 1, 64);
      int odd = er & 1;
      int d = odd ? d_o : d_e;
      int ch = odd ? (er - 1) : er;
      float lo = odd ? po : acc[r2];
      float hi = odd ? acc[r2 + 1] : pe;
      pk_atomic_add(&agg2[d * H2C + ch], lo, hi);
    }
    hsb_cur = hsb_next;
  }
}

// Fused global_add_pool + head MLP (r16-verified). batch sorted -> wave/graph.
__global__ __launch_bounds__(256) void k_poolhead(
    const _Float16* __restrict__ agg2, const int* __restrict__ batch,
    const float* __restrict__ fc1w, const float* __restrict__ fc1b,
    const float* __restrict__ outw, const float* __restrict__ outb,
    float* __restrict__ out) {
  __shared__ float s_p[4][17];
  int tid = threadIdx.x;
  int lane = tid & 63;
  int w = tid >> 6;
  int g = blockIdx.x * 4 + w;   // grid = NGRAPHS/4 exactly
  int lo = 0, hi = NNODES;
  while (lo < hi) { int m = (lo + hi) >> 1; if (batch[m] < g) lo = m + 1; else hi = m; }
  int start = lo;
  hi = NNODES;
  while (lo < hi) { int m = (lo + hi) >> 1; if (batch[m] < g + 1) lo = m + 1; else hi = m; }
  int end = lo;
  int ng = lane >> 4;
  int o = lane & 15;
  float acc = 0.f;
  for (int n = start + ng; n < end; n += 4) {
    float v = (float)agg2[n * H2C + o];
    acc += v > 0.f ? v : 0.f;
  }
  acc += __shfl_xor(acc, 16, 64);
  acc += __shfl_xor(acc, 32, 64);
  if (lane < 16) s_p[w][lane] = acc;
  float vo = 0.f;
  if (lane < 32) {
    float v = fc1b[lane];
    #pragma unroll
    for (int i = 0; i < 16; i++) v += s_p[w][i] * fc1w[i * H1C + lane];
    v = v > 0.f ? v : 0.f;
    vo = v * outw[lane];
  }
  #pragma unroll
  for (int ofs = 32; ofs >= 1; ofs >>= 1) vo += __shfl_xor(vo, ofs, 64);
  if (lane == 0) out[g] = vo + outb[0];
}

extern "C" void kernel_launch(void* const* d_in, const int* in_sizes, int n_in,
                              void* d_out, int out_size, void* d_ws, size_t ws_size,
                              hipStream_t stream) {
  const float* x      = (const float*)d_in[0];
  const int*   ei     = (const int*)d_in[1];
  const float* ea     = (const float*)d_in[2];
  const int*   batch  = (const int*)d_in[3];
  const float* c1w1   = (const float*)d_in[4];
  const float* c1b1   = (const float*)d_in[5];
  const float* c1w2   = (const float*)d_in[6];
  const float* c1b2   = (const float*)d_in[7];
  const float* c1root = (const float*)d_in[8];
  const float* c1bias = (const float*)d_in[9];
  const float* c2w1   = (const float*)d_in[10];
  const float* c2b1   = (const float*)d_in[11];
  const float* c2w2   = (const float*)d_in[12];
  const float* c2b2   = (const float*)d_in[13];
  const float* c2root = (const float*)d_in[14];
  const float* c2bias = (const float*)d_in[15];
  const float* fc1w   = (const float*)d_in[16];
  const float* fc1b   = (const float*)d_in[17];
  const float* outw   = (const float*)d_in[18];
  const float* outb   = (const float*)d_in[19];
  float* out = (float*)d_out;

  _Float16*  agg1   = (_Float16*)d_ws;                     // 6.4 MB (zeroed in k_prep)
  _Float16*  h1h    = agg1 + NNODES * H1C;                 // 6.4 MB
  _Float16*  agg2   = h1h + NNODES * H1C;                  // 3.2 MB
  _Float16*  B2h    = agg2 + NNODES * H2C;                 // 32 KB
  _Float16*  B1h    = B2h + 32 * 64 * 8;                   // 24 KB

  k_prep<<<(NNODES * H1C / 8 + 255) / 256, 256, 0, stream>>>(
      c1w2, c1b2, B1h, c2w2, B2h, agg1);
  k_edge1_mfma<<<NEDGES / 256, 256, 0, stream>>>(x, ei, ea, c1w1, c1b1, B1h, agg1);
  k_mid<<<NNODES * H2C / 256, 256, 0, stream>>>(x, agg1, c1root, c1bias,
                                                c2root, c2bias, h1h, agg2);
  k_edge2_mfma<<<(NEDGES + 511) / 512, 512, 0, stream>>>(h1h, ei, ea, c2w1, c2b1, B2h, agg2);
  k_poolhead<<<NGRAPHS / 4, 256, 0, stream>>>(agg2, batch, fc1w, fc1b, outw, outb, out);
}

// Round 18
// 138.508 us; speedup vs baseline: 1.4863x; 1.4863x over previous
//
#include <hip/hip_runtime.h>
#include <hip/hip_fp16.h>

#define NNODES 100000
#define NEDGES 800000
#define NGRAPHS 5000
#define FN 11
#define FE 4
#define H1C 32
#define H2C 16

typedef _Float16 half8 __attribute__((ext_vector_type(8)));
typedef float f32x4 __attribute__((ext_vector_type(4)));

__device__ __forceinline__ void pk_atomic_add(_Float16* p, float a, float b) {
  __half2 v = __floats2half2_rn(a, b);
  unsafeAtomicAdd(reinterpret_cast<__half2*>(p), v);
}

// Fused: zero agg1 (400k int4) + pre-swizzle B1 (12288 f16) and B2 (16384 f16).
__global__ __launch_bounds__(256) void k_prep(const float* __restrict__ c1w2,
    const float* __restrict__ c1b2, _Float16* __restrict__ B1h,
    const float* __restrict__ c2w2, _Float16* __restrict__ B2h,
    _Float16* __restrict__ agg1) {
  int t = blockIdx.x * 256 + threadIdx.x;
  if (t < NNODES * H1C / 8) {
    int4 z = {0, 0, 0, 0};
    reinterpret_cast<int4*>(agg1)[t] = z;
  }
  if (t < 2 * 12 * 64 * 8) {
    int j = t & 7;
    int lane = (t >> 3) & 63;
    int rest = t >> 9;
    int step = rest % 12;
    int ot = rest / 12;
    int q = (lane >> 4) * 8 + j;
    int o = (lane & 15) + ot * 16;
    float v;
    if (step < 11) v = c1w2[q * (FN * H1C) + step * H1C + o];
    else v = (q < FN) ? c1b2[q * H1C + o] : 0.f;
    B1h[t] = (_Float16)v;
  } else if (t < 2 * 12 * 64 * 8 + 32 * 64 * 8) {
    int t2 = t - 2 * 12 * 64 * 8;
    int kk = t2 >> 9;
    int l = (t2 >> 3) & 63;
    int j = t2 & 7;
    int i = (l >> 4) * 8 + j;
    int o = l & 15;
    B2h[t2] = (_Float16)c2w2[(kk * 32 + i) * H2C + o];
  }
}

// conv1 edge pass via MFMA — EXACT r13/r15 structure (50.5 µs verified;
// at the coalesced-atomic channel ceiling, do not touch).
__global__ __launch_bounds__(256, 3) void k_edge1_mfma(
    const float* __restrict__ x, const int* __restrict__ ei,
    const float* __restrict__ ea, const float* __restrict__ w1,
    const float* __restrict__ b1, const _Float16* __restrict__ B1h,
    _Float16* __restrict__ agg1) {
  __shared__ _Float16 Bl[12288];        // 24 KB B-frags
  __shared__ _Float16 h_sl[4][256][8];  // 16 KB h slices
  __shared__ _Float16 xs_sl[2][256][8]; // 8 KB xs slices (slices 2,3 all-zero)
  __shared__ int s_dst[256];
  int tid = threadIdx.x;
  {
    const int4* s = (const int4*)B1h;   // 1536 int4
    int4* d = (int4*)Bl;
    #pragma unroll
    for (int q = 0; q < 6; q++) d[q * 256 + tid] = s[q * 256 + tid];
  }
  int e = blockIdx.x * 256 + tid;   // NEDGES % 256 == 0
  int src = ei[e];
  s_dst[tid] = ei[NEDGES + e];
  float4 a4 = *reinterpret_cast<const float4*>(ea + e * 4);
  float h[32];
  #pragma unroll
  for (int k = 0; k < 32; k++) {
    float v = b1[k] + a4.x * w1[k] + a4.y * w1[32 + k] + a4.z * w1[64 + k] + a4.w * w1[96 + k];
    h[k] = v > 0.f ? v : 0.f;
  }
  #pragma unroll
  for (int s = 0; s < 4; s++) {
    half8 t8;
    #pragma unroll
    for (int j = 0; j < 8; j++) t8[j] = (_Float16)h[s * 8 + j];
    *reinterpret_cast<half8*>(&h_sl[s][tid][0]) = t8;
  }
  float xsv[FN];
  #pragma unroll
  for (int i = 0; i < FN; i++) xsv[i] = x[src * FN + i];
  #pragma unroll
  for (int s = 0; s < 2; s++) {
    half8 t8;
    #pragma unroll
    for (int j = 0; j < 8; j++) {
      int k = s * 8 + j;
      t8[j] = (k < FN) ? (_Float16)xsv[k] : (_Float16)0.f;
    }
    *reinterpret_cast<half8*>(&xs_sl[s][tid][0]) = t8;
  }
  __syncthreads();
  int lane = tid & 63;
  int w = tid >> 6;
  int halfk = lane >> 4;
  int er = lane & 15;
  #pragma unroll 1
  for (int g = 0; g < 4; g++) {
    int eb = w * 64 + g * 16;
    int el = eb + er;
    half8 hs8 = *reinterpret_cast<const half8*>(&h_sl[halfk][el][0]);
    half8 xs8;
    if (halfk < 2) xs8 = *reinterpret_cast<const half8*>(&xs_sl[halfk][el][0]);
    else xs8 = half8{};   // K rows 16..31 of the bias step are zero
    f32x4 acc0 = {0.f, 0.f, 0.f, 0.f};
    f32x4 acc1 = {0.f, 0.f, 0.f, 0.f};
    {
      half8 b0 = *reinterpret_cast<const half8*>(&Bl[11 * 512 + lane * 8]);
      half8 b1f = *reinterpret_cast<const half8*>(&Bl[6144 + 11 * 512 + lane * 8]);
      acc0 = __builtin_amdgcn_mfma_f32_16x16x32_f16(xs8, b0, acc0, 0, 0, 0);
      acc1 = __builtin_amdgcn_mfma_f32_16x16x32_f16(xs8, b1f, acc1, 0, 0, 0);
    }
    #pragma unroll
    for (int i = 0; i < FN; i++) {
      _Float16 xh = xs_sl[i >> 3][el][i & 7];
      half8 xsp;
      #pragma unroll
      for (int j = 0; j < 8; j++) xsp[j] = xh;
      half8 af = xsp * hs8;            // v_pk_mul_f16 x4
      half8 b0 = *reinterpret_cast<const half8*>(&Bl[i * 512 + lane * 8]);
      half8 b1f = *reinterpret_cast<const half8*>(&Bl[6144 + i * 512 + lane * 8]);
      acc0 = __builtin_amdgcn_mfma_f32_16x16x32_f16(af, b0, acc0, 0, 0, 0);
      acc1 = __builtin_amdgcn_mfma_f32_16x16x32_f16(af, b1f, acc1, 0, 0, 0);
    }
    #pragma unroll
    for (int r = 0; r < 4; r++) {
      int d = s_dst[eb + halfk * 4 + r];
      float p0 = __shfl_xor(acc0[r], 1, 64);
      float p1 = __shfl_xor(acc1[r], 1, 64);
      int odd = er & 1;
      int ch = odd ? (16 + er - 1) : er;
      float lo = odd ? p1 : acc0[r];
      float hi = odd ? acc1[r] : p0;
      pk_atomic_add(&agg1[d * H1C + ch], lo, hi);
    }
  }
}

// Fused: base = c1_bias + x@c1_root (block-staged);
// h1h = f16(relu(agg1 + base)); agg2 base = f16(c2_bias + relu@c2_root).
__global__ __launch_bounds__(256) void k_mid(const float* __restrict__ x,
    const _Float16* __restrict__ agg1, const float* __restrict__ root1,
    const float* __restrict__ bias1, const float* __restrict__ root2,
    const float* __restrict__ bias2, _Float16* __restrict__ h1h,
    _Float16* __restrict__ agg2) {
  __shared__ float sbase[16][33];
  int tid = threadIdx.x;
  int t = blockIdx.x * 256 + tid;   // NNODES*16 % 256 == 0
  int n = t >> 4, o = t & 15;
  int nl = tid >> 4;
  {
    float b0 = bias1[o], b16 = bias1[o + 16];
    #pragma unroll
    for (int i = 0; i < FN; i++) {
      float xv = x[n * FN + i];
      b0 += xv * root1[i * H1C + o];
      b16 += xv * root1[i * H1C + o + 16];
    }
    sbase[nl][o] = b0;
    sbase[nl][o + 16] = b16;
  }
  __syncthreads();
  float hv[32];
  #pragma unroll
  for (int i = 0; i < 32; i++) {
    float v = (float)agg1[n * H1C + i] + sbase[nl][i];
    hv[i] = v > 0.f ? v : 0.f;
  }
  h1h[n * H1C + o] = (_Float16)hv[o];
  h1h[n * H1C + o + 16] = (_Float16)hv[o + 16];
  float acc = bias2[o];
  #pragma unroll
  for (int i = 0; i < 32; i++) acc += hv[i] * root2[i * H2C + o];
  agg2[n * H2C + o] = (_Float16)acc;
}

// conv2 edge pass — r16-verified 256-thread structure (50.4 µs), with the
// kk accumulator SPLIT INTO TWO INDEPENDENT CHAINS (even/odd kk) to double
// MFMA ILP: breaks the 32-deep dependent-MFMA latency chain.
__global__ __launch_bounds__(256, 3) void k_edge2_mfma(
    const _Float16* __restrict__ h1h, const int* __restrict__ ei,
    const float* __restrict__ ea, const float* __restrict__ w1,
    const float* __restrict__ b1, const _Float16* __restrict__ B2h,
    _Float16* __restrict__ agg2) {
  __shared__ _Float16 Bl[16384];         // 32 KB
  __shared__ _Float16 h_sl2[4][256][8];  // 16 KB, slice-major (16B rows)
  __shared__ int s_src[256];
  __shared__ int s_dst[256];
  int tid = threadIdx.x;
  {
    const int4* s = (const int4*)B2h;    // 2048 int4
    int4* d = (int4*)Bl;
    #pragma unroll
    for (int q = 0; q < 8; q++) d[q * 256 + tid] = s[q * 256 + tid];
  }
  int e = blockIdx.x * 256 + tid;
  s_src[tid] = ei[e];
  s_dst[tid] = ei[NEDGES + e];
  float4 a4 = *reinterpret_cast<const float4*>(ea + e * 4);
  #pragma unroll
  for (int s = 0; s < 4; s++) {
    half8 t8;
    #pragma unroll
    for (int j = 0; j < 8; j++) {
      int k = s * 8 + j;
      float v = b1[k] + a4.x * w1[k] + a4.y * w1[32 + k] + a4.z * w1[64 + k] + a4.w * w1[96 + k];
      t8[j] = (_Float16)(v > 0.f ? v : 0.f);
    }
    *reinterpret_cast<half8*>(&h_sl2[s][tid][0]) = t8;
  }
  __syncthreads();
  int lane = tid & 63;
  int w = tid >> 6;
  int halfk = lane >> 4;
  int er = lane & 15;
  int sn0 = s_src[w * 64 + er];
  half8 hsb_cur = *reinterpret_cast<const half8*>(h1h + sn0 * H1C + halfk * 8);
  #pragma unroll 1
  for (int g = 0; g < 4; g++) {
    int eb = w * 64 + g * 16;
    int el = eb + er;
    half8 hsb_next = half8{};
    if (g < 3) {
      int sn2 = s_src[eb + 16 + er];
      hsb_next = *reinterpret_cast<const half8*>(h1h + sn2 * H1C + halfk * 8);
    }
    half8 hr0 = *reinterpret_cast<const half8*>(&h_sl2[0][el][0]);
    half8 hr1 = *reinterpret_cast<const half8*>(&h_sl2[1][el][0]);
    half8 hr2 = *reinterpret_cast<const half8*>(&h_sl2[2][el][0]);
    half8 hr3 = *reinterpret_cast<const half8*>(&h_sl2[3][el][0]);
    f32x4 accA = {0.f, 0.f, 0.f, 0.f};
    f32x4 accB = {0.f, 0.f, 0.f, 0.f};
    #pragma unroll
    for (int kk = 0; kk < 32; kk += 2) {
      // even chain
      {
        _Float16 hv = (kk < 8) ? hr0[kk & 7]
                    : (kk < 16) ? hr1[kk & 7]
                    : (kk < 24) ? hr2[kk & 7]
                    : hr3[kk & 7];
        half8 hsp;
        #pragma unroll
        for (int j = 0; j < 8; j++) hsp[j] = hv;
        half8 af = hsp * hsb_cur;
        half8 bfrag = *reinterpret_cast<const half8*>(&Bl[(kk * 64 + lane) * 8]);
        accA = __builtin_amdgcn_mfma_f32_16x16x32_f16(af, bfrag, accA, 0, 0, 0);
      }
      // odd chain (independent accumulator)
      {
        int k2 = kk + 1;
        _Float16 hv = (k2 < 8) ? hr0[k2 & 7]
                    : (k2 < 16) ? hr1[k2 & 7]
                    : (k2 < 24) ? hr2[k2 & 7]
                    : hr3[k2 & 7];
        half8 hsp;
        #pragma unroll
        for (int j = 0; j < 8; j++) hsp[j] = hv;
        half8 af = hsp * hsb_cur;
        half8 bfrag = *reinterpret_cast<const half8*>(&Bl[(k2 * 64 + lane) * 8]);
        accB = __builtin_amdgcn_mfma_f32_16x16x32_f16(af, bfrag, accB, 0, 0, 0);
      }
    }
    f32x4 acc;
    #pragma unroll
    for (int r = 0; r < 4; r++) acc[r] = accA[r] + accB[r];
    #pragma unroll
    for (int r2 = 0; r2 < 4; r2 += 2) {
      int d_e = s_dst[eb + halfk * 4 + r2];
      int d_o = s_dst[eb + halfk * 4 + r2 + 1];
      float pe = __shfl_xor(acc[r2], 1, 64);
      float po = __shfl_xor(acc[r2 + 1], 1, 64);
      int odd = er & 1;
      int d = odd ? d_o : d_e;
      int ch = odd ? (er - 1) : er;
      float lo = odd ? po : acc[r2];
      float hi = odd ? acc[r2 + 1] : pe;
      pk_atomic_add(&agg2[d * H2C + ch], lo, hi);
    }
    hsb_cur = hsb_next;
  }
}

// Fused global_add_pool + head MLP (r16-verified). batch sorted -> wave/graph.
__global__ __launch_bounds__(256) void k_poolhead(
    const _Float16* __restrict__ agg2, const int* __restrict__ batch,
    const float* __restrict__ fc1w, const float* __restrict__ fc1b,
    const float* __restrict__ outw, const float* __restrict__ outb,
    float* __restrict__ out) {
  __shared__ float s_p[4][17];
  int tid = threadIdx.x;
  int lane = tid & 63;
  int w = tid >> 6;
  int g = blockIdx.x * 4 + w;   // grid = NGRAPHS/4 exactly
  int lo = 0, hi = NNODES;
  while (lo < hi) { int m = (lo + hi) >> 1; if (batch[m] < g) lo = m + 1; else hi = m; }
  int start = lo;
  hi = NNODES;
  while (lo < hi) { int m = (lo + hi) >> 1; if (batch[m] < g + 1) lo = m + 1; else hi = m; }
  int end = lo;
  int ng = lane >> 4;
  int o = lane & 15;
  float acc = 0.f;
  for (int n = start + ng; n < end; n += 4) {
    float v = (float)agg2[n * H2C + o];
    acc += v > 0.f ? v : 0.f;
  }
  acc += __shfl_xor(acc, 16, 64);
  acc += __shfl_xor(acc, 32, 64);
  if (lane < 16) s_p[w][lane] = acc;
  float vo = 0.f;
  if (lane < 32) {
    float v = fc1b[lane];
    #pragma unroll
    for (int i = 0; i < 16; i++) v += s_p[w][i] * fc1w[i * H1C + lane];
    v = v > 0.f ? v : 0.f;
    vo = v * outw[lane];
  }
  #pragma unroll
  for (int ofs = 32; ofs >= 1; ofs >>= 1) vo += __shfl_xor(vo, ofs, 64);
  if (lane == 0) out[g] = vo + outb[0];
}

extern "C" void kernel_launch(void* const* d_in, const int* in_sizes, int n_in,
                              void* d_out, int out_size, void* d_ws, size_t ws_size,
                              hipStream_t stream) {
  const float* x      = (const float*)d_in[0];
  const int*   ei     = (const int*)d_in[1];
  const float* ea     = (const float*)d_in[2];
  const int*   batch  = (const int*)d_in[3];
  const float* c1w1   = (const float*)d_in[4];
  const float* c1b1   = (const float*)d_in[5];
  const float* c1w2   = (const float*)d_in[6];
  const float* c1b2   = (const float*)d_in[7];
  const float* c1root = (const float*)d_in[8];
  const float* c1bias = (const float*)d_in[9];
  const float* c2w1   = (const float*)d_in[10];
  const float* c2b1   = (const float*)d_in[11];
  const float* c2w2   = (const float*)d_in[12];
  const float* c2b2   = (const float*)d_in[13];
  const float* c2root = (const float*)d_in[14];
  const float* c2bias = (const float*)d_in[15];
  const float* fc1w   = (const float*)d_in[16];
  const float* fc1b   = (const float*)d_in[17];
  const float* outw   = (const float*)d_in[18];
  const float* outb   = (const float*)d_in[19];
  float* out = (float*)d_out;

  _Float16*  agg1   = (_Float16*)d_ws;                     // 6.4 MB (zeroed in k_prep)
  _Float16*  h1h    = agg1 + NNODES * H1C;                 // 6.4 MB
  _Float16*  agg2   = h1h + NNODES * H1C;                  // 3.2 MB
  _Float16*  B2h    = agg2 + NNODES * H2C;                 // 32 KB
  _Float16*  B1h    = B2h + 32 * 64 * 8;                   // 24 KB

  k_prep<<<(NNODES * H1C / 8 + 255) / 256, 256, 0, stream>>>(
      c1w2, c1b2, B1h, c2w2, B2h, agg1);
  k_edge1_mfma<<<NEDGES / 256, 256, 0, stream>>>(x, ei, ea, c1w1, c1b1, B1h, agg1);
  k_mid<<<NNODES * H2C / 256, 256, 0, stream>>>(x, agg1, c1root, c1bias,
                                                c2root, c2bias, h1h, agg2);
  k_edge2_mfma<<<NEDGES / 256, 256, 0, stream>>>(h1h, ei, ea, c2w1, c2b1, B2h, agg2);
  k_poolhead<<<NGRAPHS / 4, 256, 0, stream>>>(agg2, batch, fc1w, fc1b, outw, outb, out);
}